// Round 3
// baseline (235.521 us; speedup 1.0000x reference)
//
#include <hip/hip_runtime.h>

typedef __bf16 bf16x8 __attribute__((ext_vector_type(8)));
typedef float  floatx16 __attribute__((ext_vector_type(16)));

#define HW   56
#define NPIX 3136
#define CIN  128
#define COUT 256

// W2 layout: [cc(4)][tap(9)][cg(4)][oc(256)][j(8)], bf16. 576 KB of d_ws.
__global__ __launch_bounds__(256) void wt_transform_kernel(
        const float* __restrict__ Kw, __bf16* __restrict__ W2) {
    int idx = blockIdx.x * 256 + threadIdx.x;     // coalesced write
    int j     = idx & 7;
    int oc    = (idx >> 3) & 255;
    int cg    = (idx >> 11) & 3;
    int tapcc = idx >> 13;                        // cc*9 + tap
    int tap   = tapcc % 9;
    int cc    = tapcc / 9;
    int c = cc * 32 + cg * 8 + j;
    W2[idx] = (__bf16)Kw[oc * 1152 + c * 9 + tap];
}

// Xs: [row(6)][wp(66)][slot(40)] bf16; slots 0..31 = ci (cg*8+j), 32..39 pad.
// Stride 40 elems = 80 B: bank-base advances 20 banks/wp -> conflict-free b128.
__device__ __forceinline__ int xs_idx(int row, int wp, int cg) {
    return row * 2640 + wp * 40 + cg * 8;
}

// R5: mi=4 A-reuse. R2/R4 invariance (MfmaUtil pinned at 26% across different
// staging/barrier structures) points at L1/TA throughput on A-fragment loads:
// 2 KB of W2 per 128 matrix-pipe cycles per SIMD = 64 B/cyc/CU at full duty —
// saturates L1. Fix: wave tile 128 oc x 64 pos -> per kc, 4 A-loads + 2 B
// ds_reads feed 8 MFMAs (A-bytes/MFMA halved, staging bytes/MFMA halved).
// 8 independent acc chains = 256-cyc MFMA window hides load latency in-wave.
// Cost: 128 AGPR -> 2 waves/SIMD (deliberate ILP-for-TLP trade; occupancy was
// NOT the binding resource). All 4 waves read identical A addresses (L1 bcast).
__global__ __launch_bounds__(256, 2) void conv_kernel(
        const float* __restrict__ x, const __bf16* __restrict__ W2,
        const float* __restrict__ bias, float* __restrict__ out) {
    __shared__ __align__(16) __bf16 Xs[6 * 2640];   // 31.7 KB

    const int t    = threadIdx.x;
    const int nb   = blockIdx.x / 14;
    const int ht   = blockIdx.x % 14;
    const int h0   = ht * 4;
    const int ocb  = blockIdx.y * 128;

    const int wid  = t >> 6;          // 0..3
    const int lane = t & 63;
    const int half = lane >> 5;
    const int l31  = lane & 31;

    const int prow = wid;             // wave's output row (0..3); oc shared

    floatx16 acc[4][2];
    #pragma unroll
    for (int mi = 0; mi < 4; ++mi)
        #pragma unroll
        for (int nj = 0; nj < 2; ++nj)
            #pragma unroll
            for (int k = 0; k < 16; ++k)
                acc[mi][nj][k] = 0.f;

    // Zero halo columns wp==0 and wp in [57,66): 6 rows x 10 wp x 4 cg = 240.
    if (t < 240) {
        int cg   = t & 3;
        int rest = t >> 2;            // 0..59
        int row  = rest / 10;
        int zw   = rest % 10;
        int wp   = (zw == 0) ? 0 : (56 + zw);
        *(int4*)&Xs[xs_idx(row, wp, cg)] = make_int4(0, 0, 0, 0);
    }

    // Staging map: t -> (w = t&63, cg = t>>6); 6 rows x 8 c-strided loads.
    const int  sw     = t & 63;
    const int  sg     = t >> 6;       // cg uniform per wave -> clean b128 writes
    const bool wvalid = sw < 56;

    for (int cc = 0; cc < 4; ++cc) {
        __syncthreads();              // protect Xs against overwrite
        #pragma unroll
        for (int row = 0; row < 6; ++row) {
            int hin = h0 - 1 + row;
            bf16x8 v;
            #pragma unroll
            for (int j = 0; j < 8; ++j) v[j] = (__bf16)0.f;
            if (wvalid && (unsigned)hin < 56u) {
                const float* src = x + (size_t)(nb * CIN + cc * 32 + sg * 8) * NPIX
                                     + hin * HW + sw;
                #pragma unroll
                for (int j = 0; j < 8; ++j)
                    v[j] = (__bf16)src[j * NPIX];   // coalesced across lanes
            }
            if (wvalid)
                *(bf16x8*)&Xs[xs_idx(row, 1 + sw, sg)] = v;   // one ds_write_b128
        }
        __syncthreads();

        #pragma unroll
        for (int tap = 0; tap < 9; ++tap) {
            const int r = tap / 3, s = tap % 3;
            const __bf16* wtap = W2 + (size_t)(cc * 9 + tap) * (4 * 256 * 8);
            #pragma unroll
            for (int kc = 0; kc < 2; ++kc) {
                // A-fragments: 4 x 16B/lane; identical addresses across the 4
                // waves -> L1 broadcast. 8 MFMAs amortize each A/B load pair.
                bf16x8 afr[4];
                #pragma unroll
                for (int mi = 0; mi < 4; ++mi) {
                    int oc = ocb + mi * 32 + l31;
                    afr[mi] = *(const bf16x8*)(wtap + ((kc * 2 + half) * 256 + oc) * 8);
                }
                bf16x8 bfr[2];
                #pragma unroll
                for (int nj = 0; nj < 2; ++nj) {
                    int pw = nj * 32 + l31;
                    bfr[nj] = *(const bf16x8*)&Xs[xs_idx(prow + r, pw + s, kc * 2 + half)];
                }
                #pragma unroll
                for (int mi = 0; mi < 4; ++mi)
                    #pragma unroll
                    for (int nj = 0; nj < 2; ++nj)
                        acc[mi][nj] = __builtin_amdgcn_mfma_f32_32x32x16_bf16(
                            afr[mi], bfr[nj], acc[mi][nj], 0, 0, 0);
            }
        }
    }

    // Epilogue: C/D 32x32 layout col=lane&31 (pos), row=(rg&3)+8*(rg>>2)+4*half (oc).
    const float bv = bias[0];
    const int hout = h0 + prow;
    #pragma unroll
    for (int nj = 0; nj < 2; ++nj) {
        int pw = nj * 32 + l31;
        if (pw < 56) {
            #pragma unroll
            for (int mi = 0; mi < 4; ++mi) {
                #pragma unroll
                for (int rg = 0; rg < 16; ++rg) {
                    int oc = ocb + mi * 32 + (rg & 3) + ((rg >> 2) << 3) + half * 4;
                    out[(size_t)(nb * COUT + oc) * NPIX + hout * HW + pw] = acc[mi][nj][rg] + bv;
                }
            }
        }
    }
}

extern "C" void kernel_launch(void* const* d_in, const int* in_sizes, int n_in,
                              void* d_out, int out_size, void* d_ws, size_t ws_size,
                              hipStream_t stream) {
    const float* x    = (const float*)d_in[0];
    const float* Kw   = (const float*)d_in[1];
    const float* bias = (const float*)d_in[2];
    float* out = (float*)d_out;
    __bf16* W2 = (__bf16*)d_ws;   // needs 589824 bytes of workspace

    wt_transform_kernel<<<dim3(1152), dim3(256), 0, stream>>>(Kw, W2);
    conv_kernel<<<dim3(32 * 14, 2), dim3(256), 0, stream>>>(x, W2, bias, out);
}

// Round 4
// 190.212 us; speedup vs baseline: 1.2382x; 1.2382x over previous
//
#include <hip/hip_runtime.h>

typedef __bf16 bf16x8 __attribute__((ext_vector_type(8)));
typedef float  floatx16 __attribute__((ext_vector_type(16)));

#define HW   56
#define NPIX 3136
#define CIN  128
#define COUT 256

#define AS_GLOBAL __attribute__((address_space(1)))
#define AS_LDS    __attribute__((address_space(3)))

// W2 layout: [cc(4)][tap(9)][cg(4)][oc(256)][j(8)], bf16. 576 KB of d_ws.
__global__ __launch_bounds__(256) void wt_transform_kernel(
        const float* __restrict__ Kw, __bf16* __restrict__ W2) {
    int idx = blockIdx.x * 256 + threadIdx.x;     // coalesced write
    int j     = idx & 7;
    int oc    = (idx >> 3) & 255;
    int cg    = (idx >> 11) & 3;
    int tapcc = idx >> 13;                        // cc*9 + tap
    int tap   = tapcc % 9;
    int cc    = tapcc / 9;
    int c = cc * 32 + cg * 8 + j;
    W2[idx] = (__bf16)Kw[oc * 1152 + c * 9 + tap];
}

// Xs: [row(6)][wp(66)][slot(40)] bf16; slots 0..31 = ci (cg*8+j), 32..39 pad.
// Stride 40 elems = 80 B: bank-base advances 20 banks/wp -> conflict-free b128.
__device__ __forceinline__ int xs_idx(int row, int wp, int cg) {
    return row * 2640 + wp * 40 + cg * 8;
}

// R6: A (weights) moves to LDS via async global_load_lds, 3-buffer pipelined
// across taps with counted vmcnt. Diagnosis after R2=R4 invariance + R5's
// duty-vs-occupancy split: latency-bound on per-kc global A-loads (W2 from L2,
// 300-600 cyc), hidden by only ~2.75 waves/SIMD. True MFMA demand is ~14k
// cyc/SIMD vs 252k wall; no throughput pipe is near-saturated. Fix: A tap-slice
// (8 KB = 1 global_load_lds_dwordx4 x 512 thr) is DMA'd 2 taps ahead; loads
// stay in flight across raw s_barriers (vmcnt never drained below 1 mid-loop);
// inner loop reads A and B from LDS only (A contiguous 16B/lane, conflict-free).
// LDS 31.7+24 = 55.7 KB -> 2 blocks/CU; launch_bounds(512,4) pins regs <= 128
// (R4: 60 VGPR + 64 AGPR = 124, and this loop has less address math).
__global__ __launch_bounds__(512, 4) void conv_kernel(
        const float* __restrict__ x, const __bf16* __restrict__ W2,
        const float* __restrict__ bias, float* __restrict__ out) {
    __shared__ __align__(16) __bf16 Xs[6 * 2640];    // 31.7 KB
    __shared__ __align__(16) __bf16 Abuf[3][4096];   // 3 x 8 KB tap slices

    const int t    = threadIdx.x;
    const int nb   = blockIdx.x / 14;
    const int ht   = blockIdx.x % 14;
    const int h0   = ht * 4;
    const int ocb  = blockIdx.y * 128;

    const int wid  = t >> 6;          // 0..7
    const int lane = t & 63;
    const int half = lane >> 5;
    const int l31  = lane & 31;

    const int oc_rel = (wid & 1) * 64;          // wave's 64-oc slice within block
    const int prow   = wid >> 1;                // wave's output row (0..3)
    const int aocc   = (oc_rel + l31) * 8;      // A_lds elem base for this lane

    floatx16 acc[2][2];
    #pragma unroll
    for (int mi = 0; mi < 2; ++mi)
        #pragma unroll
        for (int nj = 0; nj < 2; ++nj)
            #pragma unroll
            for (int k = 0; k < 16; ++k)
                acc[mi][nj][k] = 0.f;

    // Zero halo columns wp==0 and wp in [57,66): 6 rows x 10 wp x 4 cg = 240.
    if (t < 240) {
        int cg   = t & 3;
        int rest = t >> 2;            // 0..59
        int row  = rest / 10;
        int zw   = rest % 10;
        int wp   = (zw == 0) ? 0 : (56 + zw);
        *(int4*)&Xs[xs_idx(row, wp, cg)] = make_int4(0, 0, 0, 0);
    }

    // DMA one 8 KB W2 tap-slice -> Abuf[b]. One global_load_lds_dwordx4/thread:
    // thread t covers cg = t>>7, oc' = t&127, 8 j-elems (16 B). LDS dest is
    // linear t*16 (wave-uniform base + lane*16 — the HW-required pattern).
    auto dma_a = [&](int cc, int tap, int b) {
        const __bf16* src = W2 + (size_t)(cc * 9 + tap) * 8192
                          + (t >> 7) * 2048 + (size_t)(ocb + (t & 127)) * 8;
        __builtin_amdgcn_global_load_lds(
            (const AS_GLOBAL unsigned*)(const void*)src,
            (AS_LDS unsigned*)(void*)&Abuf[b][t * 8], 16, 0, 0);
    };

    // Staging map: t -> (w = t&63, cg = (t>>6)&3, rowgroup = t>>8).
    const int  sw     = t & 63;
    const int  sgr    = t >> 6;       // 0..7
    const int  sg     = sgr & 3;      // cg, uniform per wave -> clean b128 writes
    const int  rg2    = sgr >> 2;     // 0/1 row-group
    const bool wvalid = sw < 56;

    for (int cc = 0; cc < 4; ++cc) {
        __syncthreads();              // Xs and Abuf[0..1] safe to overwrite
        // Issue A DMAs for taps 0,1 of this cc; latency hides under x staging.
        dma_a(cc, 0, 0);
        dma_a(cc, 1, 1);
        #pragma unroll
        for (int p = 0; p < 3; ++p) {
            int row = rg2 * 3 + p;    // rows 0..2 / 3..5
            int hin = h0 - 1 + row;
            bf16x8 v;
            #pragma unroll
            for (int j = 0; j < 8; ++j) v[j] = (__bf16)0.f;
            if (wvalid && (unsigned)hin < 56u) {
                const float* src = x + (size_t)(nb * CIN + cc * 32 + sg * 8) * NPIX
                                     + hin * HW + sw;
                #pragma unroll
                for (int j = 0; j < 8; ++j)
                    v[j] = (__bf16)src[j * NPIX];   // coalesced across lanes
            }
            if (wvalid)
                *(bf16x8*)&Xs[xs_idx(row, 1 + sw, sg)] = v;   // one ds_write_b128
        }
        __syncthreads();              // drains x loads AND taps 0,1 DMAs (vmcnt 0)

        #pragma unroll
        for (int tap = 0; tap < 9; ++tap) {
            // Counted drain: entering tap t (t>=2) outstanding = {t, t+1};
            // vmcnt(1) completes tap t's DMA, keeps t+1 in flight. Tail: vmcnt(0).
            if (tap >= 2) {
                if (tap == 8) asm volatile("s_waitcnt vmcnt(0)" ::: "memory");
                else          asm volatile("s_waitcnt vmcnt(1)" ::: "memory");
            }
            // Raw barrier (no auto vmcnt drain): after it, all waves' DMA
            // portions of tap t are visible AND all waves finished reading
            // tap t-1 -> buffer (t+2)%3 (holder of t-1) is reusable.
            if (tap >= 1) __builtin_amdgcn_s_barrier();
            if (tap < 7) dma_a(cc, tap + 2, (tap + 2) % 3);

            const int r = tap / 3, s = tap % 3;
            const __bf16* At = &Abuf[tap % 3][0];
            #pragma unroll
            for (int kc = 0; kc < 2; ++kc) {
                bf16x8 afr[2];
                #pragma unroll
                for (int mi = 0; mi < 2; ++mi)
                    afr[mi] = *(const bf16x8*)&At[(kc * 2 + half) * 1024 + aocc + mi * 256];
                bf16x8 bfr[2];
                #pragma unroll
                for (int nj = 0; nj < 2; ++nj) {
                    int pw = nj * 32 + l31;
                    bfr[nj] = *(const bf16x8*)&Xs[xs_idx(prow + r, pw + s, kc * 2 + half)];
                }
                #pragma unroll
                for (int mi = 0; mi < 2; ++mi)
                    #pragma unroll
                    for (int nj = 0; nj < 2; ++nj)
                        acc[mi][nj] = __builtin_amdgcn_mfma_f32_32x32x16_bf16(
                            afr[mi], bfr[nj], acc[mi][nj], 0, 0, 0);
            }
        }
    }

    // Epilogue: C/D 32x32 layout col=lane&31 (pos), row=(rg&3)+8*(rg>>2)+4*half (oc).
    const float bv = bias[0];
    const int hout = h0 + prow;
    const int oc_base = ocb + oc_rel;
    #pragma unroll
    for (int nj = 0; nj < 2; ++nj) {
        int pw = nj * 32 + l31;
        if (pw < 56) {
            #pragma unroll
            for (int mi = 0; mi < 2; ++mi) {
                #pragma unroll
                for (int rg = 0; rg < 16; ++rg) {
                    int oc = oc_base + mi * 32 + (rg & 3) + ((rg >> 2) << 3) + half * 4;
                    out[(size_t)(nb * COUT + oc) * NPIX + hout * HW + pw] = acc[mi][nj][rg] + bv;
                }
            }
        }
    }
}

extern "C" void kernel_launch(void* const* d_in, const int* in_sizes, int n_in,
                              void* d_out, int out_size, void* d_ws, size_t ws_size,
                              hipStream_t stream) {
    const float* x    = (const float*)d_in[0];
    const float* Kw   = (const float*)d_in[1];
    const float* bias = (const float*)d_in[2];
    float* out = (float*)d_out;
    __bf16* W2 = (__bf16*)d_ws;   // needs 589824 bytes of workspace

    wt_transform_kernel<<<dim3(1152), dim3(256), 0, stream>>>(Kw, W2);
    conv_kernel<<<dim3(32 * 14, 2), dim3(512), 0, stream>>>(x, W2, bias, out);
}